// Round 1
// baseline (450.267 us; speedup 1.0000x reference)
//
#include <hip/hip_runtime.h>
#include <hip/hip_bf16.h>

#define N_IN 5000
#define K_SEL 50
#define B_ROWS 16384
#define OUT_D 30

// ---------------------------------------------------------------------------
// Kernel 1: exact top-K selection of logits via 4-pass radix select (MSB->LSB)
// on monotonic-mapped fp32 keys. Single block. Writes:
//   - mask[N_IN] (k-hot, float)   -> tail of d_out
//   - idx[K_SEL] (compacted, any order) -> d_ws
// ---------------------------------------------------------------------------
__global__ __launch_bounds__(1024) void topk_mask_kernel(
    const float* __restrict__ logits,
    float* __restrict__ mask,
    int* __restrict__ idx_out)
{
    __shared__ unsigned int keys[N_IN];
    __shared__ unsigned int hist[256];
    __shared__ unsigned int s_prefix;
    __shared__ int s_remaining;
    __shared__ int s_eq_ticket;
    __shared__ int s_sel;

    const int tid = threadIdx.x;

    // Load logits -> monotonic uint keys; zero the mask output.
    for (int i = tid; i < N_IN; i += 1024) {
        unsigned int b = __float_as_uint(logits[i]);
        keys[i] = (b & 0x80000000u) ? ~b : (b | 0x80000000u);
        mask[i] = 0.0f;
    }
    if (tid == 0) { s_prefix = 0u; s_remaining = K_SEL; s_eq_ticket = 0; s_sel = 0; }
    __syncthreads();

    // 4 radix passes, 8 bits each, MSB first.
    for (int shift = 24; shift >= 0; shift -= 8) {
        for (int i = tid; i < 256; i += 1024) hist[i] = 0u;
        __syncthreads();
        const unsigned int pref = s_prefix;
        const int hi = shift + 8;  // number of already-fixed high bits boundary
        for (int i = tid; i < N_IN; i += 1024) {
            unsigned int k = keys[i];
            bool cand = (hi >= 32) ? true : ((k >> hi) == pref);
            if (cand) atomicAdd(&hist[(k >> shift) & 0xFFu], 1u);
        }
        __syncthreads();
        if (tid == 0) {
            int rem = s_remaining;
            int c = 0;
            int d = 255;
            for (;; d--) {
                int c2 = c + (int)hist[d];
                if (c2 >= rem || d == 0) {
                    s_remaining = rem - c;
                    s_prefix = (pref << 8) | (unsigned int)d;
                    break;
                }
                c = c2;
            }
        }
        __syncthreads();
    }

    const unsigned int KT = s_prefix;   // key of the K-th largest element
    const int rem = s_remaining;        // how many == KT to take (ties)

    for (int i = tid; i < N_IN; i += 1024) {
        unsigned int k = keys[i];
        bool sel = false;
        if (k > KT) {
            sel = true;
        } else if (k == KT) {
            int t = atomicAdd(&s_eq_ticket, 1);
            if (t < rem) sel = true;
        }
        if (sel) {
            int slot = atomicAdd(&s_sel, 1);
            idx_out[slot] = i;
            mask[i] = 1.0f;
        }
    }
}

// ---------------------------------------------------------------------------
// Kernel 2: gated MLP. One thread per row, one wave (64 threads) per block,
// 256 blocks -> 1 block per CU. Each thread gathers the 50 selected x values
// (50 independent loads in flight, uniform column index per load), then runs
// the 50->32->16->30 MLP fully in registers with weights staged in LDS.
// ---------------------------------------------------------------------------
__global__ __launch_bounds__(64) void gated_mlp_kernel(
    const float* __restrict__ x,
    const float* __restrict__ W1,
    const float* __restrict__ b1,
    const float* __restrict__ W2,
    const float* __restrict__ b2,
    const float* __restrict__ W3,
    const float* __restrict__ b3,
    const int* __restrict__ idx,
    float* __restrict__ out)
{
    __shared__ float sW1[K_SEL * 32];   // gathered rows of W1: [k][j]
    __shared__ float sW2[32 * 16];
    __shared__ float sW3[16 * OUT_D];
    __shared__ float sb1[32];
    __shared__ float sb2[16];
    __shared__ float sb3[OUT_D];
    __shared__ int   sidx[K_SEL];

    const int tid = threadIdx.x;

    if (tid < K_SEL) sidx[tid] = idx[tid];
    for (int t = tid; t < K_SEL * 32; t += 64) {
        int k = t >> 5;
        int j = t & 31;
        sW1[t] = W1[(size_t)idx[k] * 32 + j];
    }
    for (int t = tid; t < 32 * 16; t += 64) sW2[t] = W2[t];
    for (int t = tid; t < 16 * OUT_D; t += 64) sW3[t] = W3[t];
    if (tid < 32) sb1[tid] = b1[tid];
    if (tid < 16) sb2[tid] = b2[tid];
    if (tid < OUT_D) sb3[tid] = b3[tid];
    __syncthreads();

    const int r = blockIdx.x * 64 + tid;
    const float* __restrict__ xrow = x + (size_t)r * N_IN;

    // Gather the 50 gated inputs — 50 independent global loads.
    float xv[K_SEL];
#pragma unroll
    for (int k = 0; k < K_SEL; k++) {
        xv[k] = xrow[sidx[k]];
    }

    // Layer 1: 50 -> 32, ReLU
    float acc[32];
#pragma unroll
    for (int j = 0; j < 32; j++) acc[j] = sb1[j];
#pragma unroll
    for (int k = 0; k < K_SEL; k++) {
        float xk = xv[k];
#pragma unroll
        for (int j = 0; j < 32; j++) acc[j] = fmaf(xk, sW1[k * 32 + j], acc[j]);
    }

    // Layer 2: 32 -> 16, ReLU
    float h2[16];
#pragma unroll
    for (int j = 0; j < 16; j++) h2[j] = sb2[j];
#pragma unroll
    for (int i = 0; i < 32; i++) {
        float a = fmaxf(acc[i], 0.0f);
#pragma unroll
        for (int j = 0; j < 16; j++) h2[j] = fmaf(a, sW2[i * 16 + j], h2[j]);
    }

    // Layer 3: 16 -> 30
    float o[OUT_D];
#pragma unroll
    for (int j = 0; j < OUT_D; j++) o[j] = sb3[j];
#pragma unroll
    for (int i = 0; i < 16; i++) {
        float a = fmaxf(h2[i], 0.0f);
#pragma unroll
        for (int j = 0; j < OUT_D; j++) o[j] = fmaf(a, sW3[i * OUT_D + j], o[j]);
    }

    float* __restrict__ orow = out + (size_t)r * OUT_D;
#pragma unroll
    for (int j = 0; j < OUT_D; j++) orow[j] = o[j];
}

extern "C" void kernel_launch(void* const* d_in, const int* in_sizes, int n_in,
                              void* d_out, int out_size, void* d_ws, size_t ws_size,
                              hipStream_t stream) {
    const float* x      = (const float*)d_in[0];
    const float* logits = (const float*)d_in[1];
    const float* W1     = (const float*)d_in[2];
    const float* b1     = (const float*)d_in[3];
    const float* W2     = (const float*)d_in[4];
    const float* b2     = (const float*)d_in[5];
    const float* W3     = (const float*)d_in[6];
    const float* b3     = (const float*)d_in[7];
    // d_in[8] = epoch, d_in[9] = total_epochs — unused on the eval path.

    float* out  = (float*)d_out;                       // [16384, 30]
    float* mask = out + (size_t)B_ROWS * OUT_D;        // [5000]
    int*   idx  = (int*)d_ws;                          // [50] compacted top-k indices

    topk_mask_kernel<<<1, 1024, 0, stream>>>(logits, mask, idx);
    gated_mlp_kernel<<<256, 64, 0, stream>>>(x, W1, b1, W2, b2, W3, b3, idx, out);
}

// Round 2
// 432.035 us; speedup vs baseline: 1.0422x; 1.0422x over previous
//
#include <hip/hip_runtime.h>
#include <hip/hip_bf16.h>

#define N_IN 5000
#define K_SEL 50
#define B_ROWS 16384
#define OUT_D 30

// ---------------------------------------------------------------------------
// Kernel 1: exact top-K of logits via 32-step binary search on monotonic-
// mapped fp32 keys (kept in registers, 5/thread). No serial scans, no
// data-dependent atomic contention. Single block of 1024 threads.
// Writes: mask[N_IN] (k-hot float, tail of d_out), idx[K_SEL] (d_ws).
// ---------------------------------------------------------------------------
__global__ __launch_bounds__(1024) void topk_mask_kernel(
    const float* __restrict__ logits,
    float* __restrict__ mask,
    int* __restrict__ idx_out)
{
    __shared__ unsigned int s_cnt[34];   // one slot per binary-search step
    __shared__ int s_tick, s_sel;

    const int tid  = threadIdx.x;
    const int lane = tid & 63;

    if (tid < 34) s_cnt[tid] = 0u;
    if (tid == 40) { s_tick = 0; }
    if (tid == 41) { s_sel = 0; }

    // Load 5 keys/thread (monotonic map: order of keys == order of floats).
    unsigned int key[5];
#pragma unroll
    for (int j = 0; j < 5; j++) {
        int i = tid + j * 1024;
        if (i < N_IN) {
            unsigned int b = __float_as_uint(logits[i]);
            key[j] = (b & 0x80000000u) ? ~b : (b | 0x80000000u);
            mask[i] = 0.0f;
        } else {
            key[j] = 0u;
        }
    }
    __syncthreads();

    // Find largest T with count(key >= T) >= K. All threads track identical
    // lo/hi (branching is uniform).
    unsigned int lo = 0u, hi = 0xFFFFFFFFu;
    for (int iter = 0; iter < 32; iter++) {
        if (lo >= hi) break;   // uniform across the block
        unsigned int mid = lo + ((hi - lo) >> 1) + 1u;
        unsigned int c = 0;
#pragma unroll
        for (int j = 0; j < 5; j++) c += (key[j] >= mid) ? 1u : 0u;
#pragma unroll
        for (int off = 32; off > 0; off >>= 1) c += __shfl_down(c, off, 64);
        if (lane == 0) atomicAdd(&s_cnt[iter], c);
        __syncthreads();
        unsigned int cnt = s_cnt[iter];
        if (cnt >= (unsigned)K_SEL) lo = mid; else hi = mid - 1u;
    }
    const unsigned int KT = lo;   // key of the K-th largest element

    // rem = how many elements equal to KT we still need (tie handling).
    {
        unsigned int c = 0;
#pragma unroll
        for (int j = 0; j < 5; j++) c += (key[j] > KT) ? 1u : 0u;
#pragma unroll
        for (int off = 32; off > 0; off >>= 1) c += __shfl_down(c, off, 64);
        if (lane == 0) atomicAdd(&s_cnt[33], c);
    }
    __syncthreads();
    const int rem = K_SEL - (int)s_cnt[33];

    // Selection: key > KT always; key == KT takes a ticket.
#pragma unroll
    for (int j = 0; j < 5; j++) {
        int i = tid + j * 1024;
        if (i >= N_IN) continue;
        unsigned int k = key[j];
        bool sel = false;
        if (k > KT) {
            sel = true;
        } else if (k == KT) {
            int t = atomicAdd(&s_tick, 1);
            sel = (t < rem);
        }
        if (sel) {
            int slot = atomicAdd(&s_sel, 1);
            idx_out[slot] = i;
            mask[i] = 1.0f;
        }
    }
}

// ---------------------------------------------------------------------------
// Kernel 2: gated MLP. 256 blocks x 256 threads; each block owns 64
// consecutive rows. Gather phase: 4 threads/row, 12-13 scattered x loads each
// (lots of MLP-independent loads in flight per CU), staged to LDS with
// stride 51 (gcd(19,32)=1 -> conflict-free column reads). MLP phase: wave 0,
// one row/thread, fully in registers with weights in LDS. Coalesced float4
// epilogue through LDS.
// ---------------------------------------------------------------------------
__global__ __launch_bounds__(256) void gated_mlp_kernel(
    const float* __restrict__ x,
    const float* __restrict__ W1,
    const float* __restrict__ b1,
    const float* __restrict__ W2,
    const float* __restrict__ b2,
    const float* __restrict__ W3,
    const float* __restrict__ b3,
    const int* __restrict__ idx,
    float* __restrict__ out)
{
    __shared__ float xs[64 * 51];       // gathered gated inputs, stride 51
    __shared__ float sW1[K_SEL * 32];   // W1 rows for selected columns
    __shared__ float sW2[32 * 16];
    __shared__ float sW3[16 * OUT_D];
    __shared__ float sb1[32];
    __shared__ float sb2[16];
    __shared__ float sb3[OUT_D];
    __shared__ int   sidx[K_SEL];

    const int tid = threadIdx.x;

    // --- stage weights / indices ---
    if (tid < K_SEL) sidx[tid] = idx[tid];
    for (int e = tid; e < K_SEL * 32; e += 256) {
        int k = e >> 5, j = e & 31;
        sW1[e] = W1[(size_t)idx[k] * 32 + j];   // coalesced 128B per W1 row
    }
    for (int e = tid; e < 32 * 16; e += 256) sW2[e] = W2[e];
    for (int e = tid; e < 16 * OUT_D; e += 256) sW3[e] = W3[e];
    if (tid < 32) sb1[tid] = b1[tid];
    if (tid < 16) sb2[tid] = b2[tid];
    if (tid < OUT_D) sb3[tid] = b3[tid];
    __syncthreads();

    // --- gather: 4 threads per row, interleaved k ---
    const int r  = tid >> 2;        // row within block, 0..63
    const int q  = tid & 3;
    const int row = blockIdx.x * 64 + r;
    const float* __restrict__ xrow = x + (size_t)row * N_IN;
    for (int k = q; k < K_SEL; k += 4) {
        xs[r * 51 + k] = xrow[sidx[k]];   // independent scattered loads
    }
    __syncthreads();

    // --- MLP: wave 0, one row per thread ---
    float so_local[OUT_D];
    if (tid < 64) {
        const float* xr = &xs[tid * 51];

        float acc[32];
#pragma unroll
        for (int j = 0; j < 32; j++) acc[j] = sb1[j];
#pragma unroll
        for (int k = 0; k < K_SEL; k++) {
            float xk = xr[k];
#pragma unroll
            for (int j = 0; j < 32; j++) acc[j] = fmaf(xk, sW1[k * 32 + j], acc[j]);
        }

        float h2[16];
#pragma unroll
        for (int j = 0; j < 16; j++) h2[j] = sb2[j];
#pragma unroll
        for (int i = 0; i < 32; i++) {
            float a = fmaxf(acc[i], 0.0f);
#pragma unroll
            for (int j = 0; j < 16; j++) h2[j] = fmaf(a, sW2[i * 16 + j], h2[j]);
        }

#pragma unroll
        for (int j = 0; j < OUT_D; j++) so_local[j] = sb3[j];
#pragma unroll
        for (int i = 0; i < 16; i++) {
            float a = fmaxf(h2[i], 0.0f);
#pragma unroll
            for (int j = 0; j < OUT_D; j++) so_local[j] = fmaf(a, sW3[i * OUT_D + j], so_local[j]);
        }
    }
    __syncthreads();   // xs reuse below

    // --- coalesced epilogue: stage 64x30 to LDS, write as float4 ---
    float* so = xs;    // reuse (64*30 = 1920 floats <= 64*51)
    if (tid < 64) {
#pragma unroll
        for (int j = 0; j < OUT_D; j++) so[tid * OUT_D + j] = so_local[j];
    }
    __syncthreads();

    float4* out4 = (float4*)(out + (size_t)blockIdx.x * 64 * OUT_D);
    const float4* so4 = (const float4*)so;
    for (int e = tid; e < (64 * OUT_D) / 4; e += 256) {
        out4[e] = so4[e];
    }
}

extern "C" void kernel_launch(void* const* d_in, const int* in_sizes, int n_in,
                              void* d_out, int out_size, void* d_ws, size_t ws_size,
                              hipStream_t stream) {
    const float* x      = (const float*)d_in[0];
    const float* logits = (const float*)d_in[1];
    const float* W1     = (const float*)d_in[2];
    const float* b1     = (const float*)d_in[3];
    const float* W2     = (const float*)d_in[4];
    const float* b2     = (const float*)d_in[5];
    const float* W3     = (const float*)d_in[6];
    const float* b3     = (const float*)d_in[7];
    // d_in[8] = epoch, d_in[9] = total_epochs — unused on the eval path.

    float* out  = (float*)d_out;                       // [16384, 30]
    float* mask = out + (size_t)B_ROWS * OUT_D;        // [5000]
    int*   idx  = (int*)d_ws;                          // [50] top-k indices

    topk_mask_kernel<<<1, 1024, 0, stream>>>(logits, mask, idx);
    gated_mlp_kernel<<<256, 256, 0, stream>>>(x, W1, b1, W2, b2, W3, b3, idx, out);
}

// Round 3
// 424.101 us; speedup vs baseline: 1.0617x; 1.0187x over previous
//
#include <hip/hip_runtime.h>
#include <hip/hip_bf16.h>

#define N_IN 5000
#define K_SEL 50
#define B_ROWS 16384
#define OUT_D 30

// ---------------------------------------------------------------------------
// Kernel 1: exact top-K of logits via binary search on monotonic-mapped fp32
// keys (20/thread in registers). Early exit when count(>=mid)==K (typical:
// ~17 iters, no tie handling needed). 1 block x 256 threads (4 waves).
// Writes: mask[N_IN] (k-hot float, tail of d_out), idx[K_SEL] (d_ws).
// ---------------------------------------------------------------------------
__global__ __launch_bounds__(256) void topk_mask_kernel(
    const float* __restrict__ logits,
    float* __restrict__ mask,
    int* __restrict__ idx_out)
{
    __shared__ unsigned int s_cnt[36];
    __shared__ int s_tick, s_sel;

    const int tid  = threadIdx.x;
    const int lane = tid & 63;

    if (tid < 36) s_cnt[tid] = 0u;
    if (tid == 40) s_tick = 0;
    if (tid == 41) s_sel = 0;

    // 20 keys/thread (monotonic map: uint order == float order).
    unsigned int key[20];
#pragma unroll
    for (int j = 0; j < 20; j++) {
        int i = tid + j * 256;
        if (i < N_IN) {
            unsigned int b = __float_as_uint(logits[i]);
            key[j] = (b & 0x80000000u) ? ~b : (b | 0x80000000u);
            mask[i] = 0.0f;
        } else {
            key[j] = 0u;
        }
    }
    __syncthreads();

    // Largest T with count(key >= T) >= K; early-exit if count == K exactly.
    unsigned int lo = 0u, hi = 0xFFFFFFFFu;
    bool exact = false;
    unsigned int T;
    for (int iter = 0; iter < 32; iter++) {
        if (lo >= hi) break;                       // uniform
        unsigned int mid = lo + ((hi - lo) >> 1) + 1u;
        unsigned int c = 0;
#pragma unroll
        for (int j = 0; j < 20; j++) c += (key[j] >= mid) ? 1u : 0u;
#pragma unroll
        for (int off = 32; off > 0; off >>= 1) c += __shfl_down(c, off, 64);
        if (lane == 0) atomicAdd(&s_cnt[iter], c);
        __syncthreads();
        unsigned int cnt = s_cnt[iter];
        if (cnt == (unsigned)K_SEL) { T = mid; exact = true; break; }  // uniform
        if (cnt > (unsigned)K_SEL) lo = mid; else hi = mid - 1u;
    }

    if (exact) {
        // Selection is exactly {key >= T}: deterministic, no tickets.
#pragma unroll
        for (int j = 0; j < 20; j++) {
            int i = tid + j * 256;
            if (i < N_IN && key[j] >= T) {
                int slot = atomicAdd(&s_sel, 1);
                idx_out[slot] = i;
                mask[i] = 1.0f;
            }
        }
        return;
    }

    const unsigned int KT = lo;   // key of the K-th largest (with ties)
    {
        unsigned int c = 0;
#pragma unroll
        for (int j = 0; j < 20; j++) c += (key[j] > KT) ? 1u : 0u;
#pragma unroll
        for (int off = 32; off > 0; off >>= 1) c += __shfl_down(c, off, 64);
        if (lane == 0) atomicAdd(&s_cnt[35], c);
    }
    __syncthreads();
    const int rem = K_SEL - (int)s_cnt[35];

#pragma unroll
    for (int j = 0; j < 20; j++) {
        int i = tid + j * 256;
        if (i >= N_IN) continue;
        unsigned int k = key[j];
        bool sel = false;
        if (k > KT) sel = true;
        else if (k == KT) { int t = atomicAdd(&s_tick, 1); sel = (t < rem); }
        if (sel) {
            int slot = atomicAdd(&s_sel, 1);
            idx_out[slot] = i;
            mask[i] = 1.0f;
        }
    }
}

// ---------------------------------------------------------------------------
// Kernel 2: gated MLP. 256 blocks x 256 threads, 64 rows/block.
// Gather: 4 threads/row, FULLY UNROLLED 13 loads -> registers -> ds_write
// (one HBM latency instead of 13 serialized round-trips).
// MLP: j-partitioned across all 256 threads (4 waves busy, not 1):
//   L1: thread=(row, 8-wide j chunk), h1 -> LDS stride 33
//   L2: thread=(row, 4-wide j chunk), h2 -> LDS stride 17
//   L3: thread=(row, 8/6-wide j chunk) -> LDS staging -> float4 epilogue
// ---------------------------------------------------------------------------
__global__ __launch_bounds__(256) void gated_mlp_kernel(
    const float* __restrict__ x,
    const float* __restrict__ W1,
    const float* __restrict__ b1,
    const float* __restrict__ W2,
    const float* __restrict__ b2,
    const float* __restrict__ W3,
    const float* __restrict__ b3,
    const int* __restrict__ idx,
    float* __restrict__ out)
{
    __shared__ float xs[64 * 51];       // gathered gated inputs (stride 51)
    __shared__ float h1s[64 * 33];      // relu(L1) (stride 33)
    __shared__ float h2s[64 * 17];      // relu(L2) (stride 17)
    __shared__ float sW1[K_SEL * 32];
    __shared__ float sW2[32 * 16];
    __shared__ float sW3[16 * OUT_D];
    __shared__ float sb1[32];
    __shared__ float sb2[16];
    __shared__ float sb3[OUT_D];
    __shared__ int   sidx[K_SEL];

    const int tid = threadIdx.x;

    // --- stage weights / indices ---
    if (tid < K_SEL) sidx[tid] = idx[tid];
    for (int e = tid; e < K_SEL * 32; e += 256) {
        int k = e >> 5, j = e & 31;
        sW1[e] = W1[(size_t)idx[k] * 32 + j];   // coalesced 128B per W1 row
    }
    for (int e = tid; e < 32 * 16; e += 256) sW2[e] = W2[e];
    for (int e = tid; e < 16 * OUT_D; e += 256) sW3[e] = W3[e];
    if (tid < 32) sb1[tid] = b1[tid];
    if (tid < 16) sb2[tid] = b2[tid];
    if (tid < OUT_D) sb3[tid] = b3[tid];
    __syncthreads();

    // --- gather: 4 threads/row, 13 unrolled loads -> regs -> LDS ---
    {
        const int r = tid >> 2;          // 0..63
        const int q = tid & 3;
        const int row = blockIdx.x * 64 + r;
        const float* __restrict__ xrow = x + (size_t)row * N_IN;
        float g[13];
#pragma unroll
        for (int u = 0; u < 13; u++) {
            int k = q * 13 + u;
            if (k < K_SEL) g[u] = xrow[sidx[k]];
        }
#pragma unroll
        for (int u = 0; u < 13; u++) {
            int k = q * 13 + u;
            if (k < K_SEL) xs[r * 51 + k] = g[u];
        }
    }
    __syncthreads();

    const int r = tid & 63;              // row within block
    const int c = tid >> 6;              // j-chunk / wave id, 0..3

    // --- L1: 50 -> 32, relu. 8 outputs/thread ---
    {
        float acc[8];
#pragma unroll
        for (int jj = 0; jj < 8; jj++) acc[jj] = sb1[c * 8 + jj];
        const float* xr = &xs[r * 51];
        for (int k = 0; k < K_SEL; k++) {
            float xk = xr[k];                      // stride-51 lanes: conflict-free
            const float* w = &sW1[k * 32 + c * 8]; // wave-uniform: broadcast
#pragma unroll
            for (int jj = 0; jj < 8; jj++) acc[jj] = fmaf(xk, w[jj], acc[jj]);
        }
#pragma unroll
        for (int jj = 0; jj < 8; jj++) h1s[r * 33 + c * 8 + jj] = fmaxf(acc[jj], 0.0f);
    }
    __syncthreads();

    // --- L2: 32 -> 16, relu. 4 outputs/thread ---
    {
        float acc[4];
#pragma unroll
        for (int jj = 0; jj < 4; jj++) acc[jj] = sb2[c * 4 + jj];
        const float* hr = &h1s[r * 33];
#pragma unroll
        for (int i = 0; i < 32; i++) {
            float a = hr[i];
            const float* w = &sW2[i * 16 + c * 4];
#pragma unroll
            for (int jj = 0; jj < 4; jj++) acc[jj] = fmaf(a, w[jj], acc[jj]);
        }
#pragma unroll
        for (int jj = 0; jj < 4; jj++) h2s[r * 17 + c * 4 + jj] = fmaxf(acc[jj], 0.0f);
    }
    __syncthreads();

    // --- L3: 16 -> 30. 8 outputs/thread (6 for c==3), staged into xs ---
    {
        const int j0 = c * 8;
        const int nj = (c == 3) ? 6 : 8;
        float acc[8];
        for (int jj = 0; jj < nj; jj++) acc[jj] = sb3[j0 + jj];
        const float* hr = &h2s[r * 17];
#pragma unroll
        for (int i = 0; i < 16; i++) {
            float a = hr[i];
            const float* w = &sW3[i * OUT_D + j0];
            for (int jj = 0; jj < nj; jj++) acc[jj] = fmaf(a, w[jj], acc[jj]);
        }
        float* so = xs;                  // reuse: 64*30 = 1920 <= 64*51
        for (int jj = 0; jj < nj; jj++) so[r * OUT_D + j0 + jj] = acc[jj];
    }
    __syncthreads();

    // --- coalesced float4 epilogue: 64 rows x 30 floats = 480 float4 ---
    {
        float4* out4 = (float4*)(out + (size_t)blockIdx.x * 64 * OUT_D);
        const float4* so4 = (const float4*)xs;
        for (int e = tid; e < (64 * OUT_D) / 4; e += 256) out4[e] = so4[e];
    }
}

extern "C" void kernel_launch(void* const* d_in, const int* in_sizes, int n_in,
                              void* d_out, int out_size, void* d_ws, size_t ws_size,
                              hipStream_t stream) {
    const float* x      = (const float*)d_in[0];
    const float* logits = (const float*)d_in[1];
    const float* W1     = (const float*)d_in[2];
    const float* b1     = (const float*)d_in[3];
    const float* W2     = (const float*)d_in[4];
    const float* b2     = (const float*)d_in[5];
    const float* W3     = (const float*)d_in[6];
    const float* b3     = (const float*)d_in[7];
    // d_in[8] = epoch, d_in[9] = total_epochs — unused on the eval path.

    float* out  = (float*)d_out;                       // [16384, 30]
    float* mask = out + (size_t)B_ROWS * OUT_D;        // [5000]
    int*   idx  = (int*)d_ws;                          // [50] top-k indices

    topk_mask_kernel<<<1, 256, 0, stream>>>(logits, mask, idx);
    gated_mlp_kernel<<<256, 256, 0, stream>>>(x, W1, b1, W2, b2, W3, b3, idx, out);
}

// Round 4
// 421.286 us; speedup vs baseline: 1.0688x; 1.0067x over previous
//
#include <hip/hip_runtime.h>
#include <hip/hip_bf16.h>

#define N_IN 5000
#define K_SEL 50
#define B_ROWS 16384
#define OUT_D 30

// ---------------------------------------------------------------------------
// Single fused kernel: 256 blocks x 256 threads, 64 rows/block.
//
// Phase A (per-block redundant top-k): every block reads the 5000 logits
// (L2/LLC-resident after the first block) and runs a binary search on
// monotonic-mapped uint keys (20/thread in registers) with early exit when
// count(>=mid)==K. With distinct inputs the selected SET is deterministic;
// block-internal order (LDS-atomic tickets) only needs to be consistent
// between this block's W1 gather and x gather — which it is, via sidx[].
// Block 0 additionally writes the k-hot mask output. Removing the separate
// top-k kernel kills a launch + 1-CU serialization (~5-8 us).
//
// Phase B (gather): W1 rows for selected columns -> LDS (coalesced 128B
// rows); x gather with 4 threads/row, 13 fully-unrolled loads -> registers
// -> ds_write (one HBM latency, not 13 round trips). Duplicate lines within
// a row hit L2, so HBM traffic ~= unique 64-128B lines: ~45-105 MB total.
//
// Phase C (MLP): j-partitioned across all 4 waves; h1/h2 round-trip through
// padded LDS (strides 51/33/17 -> conflict-free); float4 epilogue.
// ---------------------------------------------------------------------------
__global__ __launch_bounds__(256) void fused_gated_mlp_kernel(
    const float* __restrict__ x,
    const float* __restrict__ logits,
    const float* __restrict__ W1,
    const float* __restrict__ b1,
    const float* __restrict__ W2,
    const float* __restrict__ b2,
    const float* __restrict__ W3,
    const float* __restrict__ b3,
    float* __restrict__ out,
    float* __restrict__ mask)
{
    __shared__ float xs[64 * 51];       // gathered gated inputs (stride 51)
    __shared__ float h1s[64 * 33];      // relu(L1) (stride 33)
    __shared__ float h2s[64 * 17];      // relu(L2) (stride 17)
    __shared__ float sW1[K_SEL * 32];
    __shared__ float sW2[32 * 16];
    __shared__ float sW3[16 * OUT_D];
    __shared__ float sb1[32];
    __shared__ float sb2[16];
    __shared__ float sb3[OUT_D];
    __shared__ int   sidx[K_SEL];
    __shared__ unsigned int s_cnt[36];
    __shared__ int s_tick, s_sel;

    const int tid  = threadIdx.x;
    const int lane = tid & 63;

    if (tid < 36) s_cnt[tid] = 0u;
    if (tid == 40) s_tick = 0;
    if (tid == 41) s_sel = 0;

    // --- idx-independent weight staging: loads overlap the top-k phase ---
    for (int e = tid; e < 32 * 16; e += 256) sW2[e] = W2[e];
    for (int e = tid; e < 16 * OUT_D; e += 256) sW3[e] = W3[e];
    if (tid < 32) sb1[tid] = b1[tid];
    if (tid < 16) sb2[tid] = b2[tid];
    if (tid < OUT_D) sb3[tid] = b3[tid];

    // --- Phase A: top-k. 20 keys/thread, monotonic uint map ---
    unsigned int key[20];
#pragma unroll
    for (int j = 0; j < 20; j++) {
        int i = tid + j * 256;
        if (i < N_IN) {
            unsigned int b = __float_as_uint(logits[i]);
            key[j] = (b & 0x80000000u) ? ~b : (b | 0x80000000u);
        } else {
            key[j] = 0u;
        }
    }
    __syncthreads();

    unsigned int lo = 0u, hi = 0xFFFFFFFFu;
    bool exact = false;
    unsigned int T = 0;
    for (int iter = 0; iter < 32; iter++) {
        if (lo >= hi) break;                         // uniform
        unsigned int mid = lo + ((hi - lo) >> 1) + 1u;
        unsigned int c = 0;
#pragma unroll
        for (int j = 0; j < 20; j++) c += (key[j] >= mid) ? 1u : 0u;
#pragma unroll
        for (int off = 32; off > 0; off >>= 1) c += __shfl_down(c, off, 64);
        if (lane == 0) atomicAdd(&s_cnt[iter], c);
        __syncthreads();
        unsigned int cnt = s_cnt[iter];
        if (cnt == (unsigned)K_SEL) { T = mid; exact = true; break; }  // uniform
        if (cnt > (unsigned)K_SEL) lo = mid; else hi = mid - 1u;
    }

    const bool write_mask = (blockIdx.x == 0);
    if (exact) {
        // Selection set is exactly {key >= T}: deterministic.
#pragma unroll
        for (int j = 0; j < 20; j++) {
            int i = tid + j * 256;
            if (i >= N_IN) continue;
            bool sel = (key[j] >= T);
            if (sel) { int s = atomicAdd(&s_sel, 1); sidx[s] = i; }
            if (write_mask) mask[i] = sel ? 1.0f : 0.0f;
        }
    } else {
        const unsigned int KT = lo;
        unsigned int c = 0;
#pragma unroll
        for (int j = 0; j < 20; j++) c += (key[j] > KT) ? 1u : 0u;
#pragma unroll
        for (int off = 32; off > 0; off >>= 1) c += __shfl_down(c, off, 64);
        if (lane == 0) atomicAdd(&s_cnt[35], c);
        __syncthreads();
        const int rem = K_SEL - (int)s_cnt[35];
#pragma unroll
        for (int j = 0; j < 20; j++) {
            int i = tid + j * 256;
            if (i >= N_IN) continue;
            unsigned int k = key[j];
            bool sel = false;
            if (k > KT) sel = true;
            else if (k == KT) { int t = atomicAdd(&s_tick, 1); sel = (t < rem); }
            if (sel) { int s = atomicAdd(&s_sel, 1); sidx[s] = i; }
            if (write_mask) mask[i] = sel ? 1.0f : 0.0f;
        }
    }
    __syncthreads();   // sidx complete

    // --- Phase B: gathers ---
    for (int e = tid; e < K_SEL * 32; e += 256) {
        int k = e >> 5, j = e & 31;
        sW1[e] = W1[(size_t)sidx[k] * 32 + j];   // coalesced 128B per W1 row
    }
    {
        const int r = tid >> 2;          // 0..63
        const int q = tid & 3;
        const int row = blockIdx.x * 64 + r;
        const float* __restrict__ xrow = x + (size_t)row * N_IN;
        float g[13];
#pragma unroll
        for (int u = 0; u < 13; u++) {
            int k = q * 13 + u;
            if (k < K_SEL) g[u] = xrow[sidx[k]];
        }
#pragma unroll
        for (int u = 0; u < 13; u++) {
            int k = q * 13 + u;
            if (k < K_SEL) xs[r * 51 + k] = g[u];
        }
    }
    __syncthreads();

    const int r = tid & 63;              // row within block
    const int c = tid >> 6;              // j-chunk / wave id, 0..3

    // --- L1: 50 -> 32, relu. 8 outputs/thread ---
    {
        float acc[8];
#pragma unroll
        for (int jj = 0; jj < 8; jj++) acc[jj] = sb1[c * 8 + jj];
        const float* xr = &xs[r * 51];
        for (int k = 0; k < K_SEL; k++) {
            float xk = xr[k];                      // stride-51: conflict-free
            const float* w = &sW1[k * 32 + c * 8]; // wave-uniform: broadcast
#pragma unroll
            for (int jj = 0; jj < 8; jj++) acc[jj] = fmaf(xk, w[jj], acc[jj]);
        }
#pragma unroll
        for (int jj = 0; jj < 8; jj++) h1s[r * 33 + c * 8 + jj] = fmaxf(acc[jj], 0.0f);
    }
    __syncthreads();

    // --- L2: 32 -> 16, relu. 4 outputs/thread ---
    {
        float acc[4];
#pragma unroll
        for (int jj = 0; jj < 4; jj++) acc[jj] = sb2[c * 4 + jj];
        const float* hr = &h1s[r * 33];
#pragma unroll
        for (int i = 0; i < 32; i++) {
            float a = hr[i];
            const float* w = &sW2[i * 16 + c * 4];
#pragma unroll
            for (int jj = 0; jj < 4; jj++) acc[jj] = fmaf(a, w[jj], acc[jj]);
        }
#pragma unroll
        for (int jj = 0; jj < 4; jj++) h2s[r * 17 + c * 4 + jj] = fmaxf(acc[jj], 0.0f);
    }
    __syncthreads();

    // --- L3: 16 -> 30. 8 outputs/thread (6 for c==3), staged into xs ---
    {
        const int j0 = c * 8;
        const int nj = (c == 3) ? 6 : 8;
        float acc[8];
        for (int jj = 0; jj < nj; jj++) acc[jj] = sb3[j0 + jj];
        const float* hr = &h2s[r * 17];
#pragma unroll
        for (int i = 0; i < 16; i++) {
            float a = hr[i];
            const float* w = &sW3[i * OUT_D + j0];
            for (int jj = 0; jj < nj; jj++) acc[jj] = fmaf(a, w[jj], acc[jj]);
        }
        float* so = xs;                  // reuse: 64*30 = 1920 <= 64*51
        for (int jj = 0; jj < nj; jj++) so[r * OUT_D + j0 + jj] = acc[jj];
    }
    __syncthreads();

    // --- coalesced float4 epilogue: 64 rows x 30 floats = 480 float4 ---
    {
        float4* out4 = (float4*)(out + (size_t)blockIdx.x * 64 * OUT_D);
        const float4* so4 = (const float4*)xs;
        for (int e = tid; e < (64 * OUT_D) / 4; e += 256) out4[e] = so4[e];
    }
}

extern "C" void kernel_launch(void* const* d_in, const int* in_sizes, int n_in,
                              void* d_out, int out_size, void* d_ws, size_t ws_size,
                              hipStream_t stream) {
    const float* x      = (const float*)d_in[0];
    const float* logits = (const float*)d_in[1];
    const float* W1     = (const float*)d_in[2];
    const float* b1     = (const float*)d_in[3];
    const float* W2     = (const float*)d_in[4];
    const float* b2     = (const float*)d_in[5];
    const float* W3     = (const float*)d_in[6];
    const float* b3     = (const float*)d_in[7];
    // d_in[8] = epoch, d_in[9] = total_epochs — unused on the eval path.

    float* out  = (float*)d_out;                       // [16384, 30]
    float* mask = out + (size_t)B_ROWS * OUT_D;        // [5000]

    fused_gated_mlp_kernel<<<256, 256, 0, stream>>>(
        x, logits, W1, b1, W2, b2, W3, b3, out, mask);
}